// Round 6
// baseline (414.158 us; speedup 1.0000x reference)
//
#include <hip/hip_runtime.h>

#define NN 100000
#define EE 600000
#define GG 1000
#define NB ((NN + 255) / 256)   // 391 blocks; also covers NN+1 scan elements

typedef __bf16 bf16x8 __attribute__((ext_vector_type(8)));
typedef float f32x4 __attribute__((ext_vector_type(4)));
typedef unsigned int u32;

__device__ inline float2 bf2_to_f2(u32 u) {
  return make_float2(__uint_as_float(u << 16), __uint_as_float(u & 0xffff0000u));
}
__device__ inline u32 f2_to_bf2(float a, float b) {
  union { __bf16 h[2]; u32 u; } pk;
  pk.h[0] = (__bf16)a; pk.h[1] = (__bf16)b;   // RNE converts
  return pk.u;
}

// ---------------- setup kernels (CSR build + norm) ----------------

__global__ void k_init(int* cnt, int* fillc, int* gstart) {
  int i = blockIdx.x * 256 + threadIdx.x;
  if (i < NN) { cnt[i] = 0; fillc[i] = 0; }
  if (i <= GG) gstart[i] = NN;
}

__global__ void k_count(const int* __restrict__ dst, int* cnt) {
  int e = blockIdx.x * 256 + threadIdx.x;
  if (e < EE) atomicAdd(&cnt[dst[e]], 1);
}

// scan over NN+1 elements of padded counts ((cnt+7)&~7); also computes dinv
__global__ void k_scan1(const int* __restrict__ cnt, float* __restrict__ dinv,
                        int* rowptr, int* bsum) {
  __shared__ int s[256];
  int tid = threadIdx.x;
  int i = blockIdx.x * 256 + tid;
  int v = (i < NN) ? ((cnt[i] + 7) & ~7) : 0;
  if (i < NN) dinv[i] = rsqrtf((float)(cnt[i] + 1));  // +1 = self loop
  s[tid] = v;
  __syncthreads();
  for (int off = 1; off < 256; off <<= 1) {
    int t = (tid >= off) ? s[tid - off] : 0;
    __syncthreads();
    s[tid] += t;
    __syncthreads();
  }
  if (i <= NN) rowptr[i] = s[tid] - v;
  if (tid == 255) bsum[blockIdx.x] = s[255];
}

__global__ void k_scan2(int* bsum) {
  __shared__ int s[512];
  int tid = threadIdx.x;
  int v = (tid < NB) ? bsum[tid] : 0;
  s[tid] = v;
  __syncthreads();
  for (int off = 1; off < 512; off <<= 1) {
    int t = (tid >= off) ? s[tid - off] : 0;
    __syncthreads();
    s[tid] += t;
    __syncthreads();
  }
  if (tid < NB) bsum[tid] = s[tid] - v;
}

__global__ void k_scan3(int* rowptr, const int* __restrict__ bsum) {
  int i = blockIdx.x * 256 + threadIdx.x;
  if (i <= NN) rowptr[i] += bsum[blockIdx.x];
}

// fill CSR (edge-parallel) + pad each node's segment to x8 (node-parallel)
__global__ void k_fillpad(const int* __restrict__ src, const int* __restrict__ dst,
                          const int* __restrict__ rowptr, int* fillc,
                          const int* __restrict__ cnt,
                          const float* __restrict__ dinv,
                          int2* __restrict__ csr) {
  int gid = blockIdx.x * 256 + threadIdx.x;
  if (gid < EE) {
    int s = src[gid], d = dst[gid];
    int pos = rowptr[d] + atomicAdd(&fillc[d], 1);
    csr[pos] = make_int2(s, __float_as_int(dinv[s] * dinv[d]));
  }
  if (gid < NN) {
    int2 pad = make_int2(gid, 0);   // w=0: no-op edge pointing at self (L1-hot)
    for (int pos = rowptr[gid] + cnt[gid]; pos < rowptr[gid + 1]; ++pos)
      csr[pos] = pad;
  }
}

__global__ void k_gbound(const int* __restrict__ batch, int* gstart) {
  int i = blockIdx.x * 256 + threadIdx.x;
  if (i >= NN) return;
  int b = batch[i];
  if (i == 0) {
    for (int g = 0; g <= b; ++g) gstart[g] = 0;
  } else {
    int prev = batch[i - 1];
    for (int g = prev + 1; g <= b; ++g) gstart[g] = i;
  }
}

// transpose W [128k x 128n] fp32 -> Wt [n][k] bf16 (one-time per layer)
__global__ void k_wprep(const float* __restrict__ W, __bf16* __restrict__ Wt) {
  int idx = blockIdx.x * 256 + threadIdx.x;   // 16384
  int n = idx >> 7, k = idx & 127;
  Wt[(size_t)n * 128 + k] = (__bf16)W[(size_t)k * 128 + n];
}

// ---------------- layer kernels ----------------

// layer-0 linear: [N,4] @ [4,128] -> bf16 hout (bias added in aggregate)
__global__ void k_mm0(const float* __restrict__ x, const float* __restrict__ W0,
                      __bf16* __restrict__ hout) {
  int idx = blockIdx.x * 256 + threadIdx.x;
  if (idx >= NN * 128) return;
  int node = idx >> 7, j = idx & 127;
  const float* xr = x + node * 4;
  float s = xr[0] * W0[j];
  s = fmaf(xr[1], W0[128 + j], s);
  s = fmaf(xr[2], W0[256 + j], s);
  s = fmaf(xr[3], W0[384 + j], s);
  hout[idx] = (__bf16)s;
}

// MFMA GEMM: hout[N,128] = hin[N,128] @ W, bf16 in/out, fp32 accum.
#define LDSPAD 136
__global__ __launch_bounds__(256) void k_mfma(const __bf16* __restrict__ hin,
                                              const __bf16* __restrict__ Wt,
                                              __bf16* __restrict__ hout) {
  __shared__ __bf16 As[128 * LDSPAD];   // 34 KB
  int tid = threadIdx.x;
  int row0 = blockIdx.x * 128;
  int lane = tid & 63, w = tid >> 6;
  int ln = lane & 15, quad = lane >> 4;

  bf16x8 bfrag[8][4];
  #pragma unroll
  for (int nt = 0; nt < 8; ++nt)
    #pragma unroll
    for (int kc = 0; kc < 4; ++kc)
      bfrag[nt][kc] = *(const bf16x8*)(Wt + (size_t)(nt * 16 + ln) * 128 + kc * 32 + quad * 8);

  #pragma unroll
  for (int i = 0; i < 8; ++i) {
    int eb = (i * 256 + tid) * 8;
    int r = eb >> 7, c = eb & 127;
    int gr = row0 + r;
    uint4 v = make_uint4(0, 0, 0, 0);
    if (gr < NN) v = *(const uint4*)(hin + (size_t)gr * 128 + c);
    *(uint4*)&As[r * LDSPAD + c] = v;
  }
  __syncthreads();

  f32x4 acc[2][8];
  #pragma unroll
  for (int rt = 0; rt < 2; ++rt)
    #pragma unroll
    for (int nt = 0; nt < 8; ++nt) acc[rt][nt] = (f32x4){0.f, 0.f, 0.f, 0.f};

  #pragma unroll
  for (int kc = 0; kc < 4; ++kc) {
    bf16x8 a0 = *(const bf16x8*)&As[(w * 32 + ln) * LDSPAD + kc * 32 + quad * 8];
    bf16x8 a1 = *(const bf16x8*)&As[(w * 32 + 16 + ln) * LDSPAD + kc * 32 + quad * 8];
    #pragma unroll
    for (int nt = 0; nt < 8; ++nt) {
      acc[0][nt] = __builtin_amdgcn_mfma_f32_16x16x32_bf16(a0, bfrag[nt][kc], acc[0][nt], 0, 0, 0);
      acc[1][nt] = __builtin_amdgcn_mfma_f32_16x16x32_bf16(a1, bfrag[nt][kc], acc[1][nt], 0, 0, 0);
    }
  }

  #pragma unroll
  for (int rt = 0; rt < 2; ++rt)
    #pragma unroll
    for (int nt = 0; nt < 8; ++nt)
      #pragma unroll
      for (int reg = 0; reg < 4; ++reg) {
        int gr = row0 + w * 32 + rt * 16 + quad * 4 + reg;
        if (gr < NN)
          hout[(size_t)gr * 128 + nt * 16 + ln] = (__bf16)acc[rt][nt][reg];
      }
}

// out[i] = relu(b + dinv[i]^2*h[i] + sum_e w[e]*h[src[e]]) -> bf16
// One wave per node. Quad q gathers edge j+q (16 lanes x 16B = full 256B row),
// so one dwordx4 instruction fetches 4 edges; unroll x2 -> 8 edges / 2 loads
// in flight. CSR segments padded to x8 (w=0 self edges) -> no tail masking.
// Per-quad metadata via ds_bpermute from the cooperatively-loaded chunk.
__global__ __launch_bounds__(256) void k_aggregate(const __bf16* __restrict__ hlin,
                                                   const int* __restrict__ rowptr,
                                                   const int2* __restrict__ csr,
                                                   const float* __restrict__ dinv,
                                                   const float* __restrict__ bias,
                                                   u32* __restrict__ hout2) {
  int node = blockIdx.x * 4 + (threadIdx.x >> 6);
  int lane = threadIdx.x & 63;
  int ln = lane & 15, quad = lane >> 4;
  if (node >= NN) return;
  float di = dinv[node];
  float sw = di * di;

  // self + bias (quad 0 only; other quads start at zero)
  uint4 su = *(const uint4*)(hlin + ((size_t)node << 7) + ln * 8);
  float4 ba = *(const float4*)(bias + ln * 8);
  float4 bb = *(const float4*)(bias + ln * 8 + 4);
  float2 s0 = bf2_to_f2(su.x), s1 = bf2_to_f2(su.y);
  float2 s2 = bf2_to_f2(su.z), s3 = bf2_to_f2(su.w);
  float q0 = (quad == 0) ? 1.f : 0.f;
  float acc[8];
  acc[0] = q0 * fmaf(sw, s0.x, ba.x); acc[1] = q0 * fmaf(sw, s0.y, ba.y);
  acc[2] = q0 * fmaf(sw, s1.x, ba.z); acc[3] = q0 * fmaf(sw, s1.y, ba.w);
  acc[4] = q0 * fmaf(sw, s2.x, bb.x); acc[5] = q0 * fmaf(sw, s2.y, bb.y);
  acc[6] = q0 * fmaf(sw, s3.x, bb.z); acc[7] = q0 * fmaf(sw, s3.y, bb.w);

  int beg = rowptr[node], end = rowptr[node + 1];
  for (int base = beg; base < end; base += 64) {
    int m = end - base; if (m > 64) m = 64;           // multiple of 8
    int li = base + (lane < m ? lane : m - 1);
    int2 md = csr[li];                                // one coalesced 8B load
    int idxv = md.x, wbits = md.y;
    for (int j = 0; j < m; j += 8) {
      int sl0 = (j + quad) * 4, sl1 = (j + 4 + quad) * 4;
      int r0 = __builtin_amdgcn_ds_bpermute(sl0, idxv);
      int r1 = __builtin_amdgcn_ds_bpermute(sl1, idxv);
      float w0 = __int_as_float(__builtin_amdgcn_ds_bpermute(sl0, wbits));
      float w1 = __int_as_float(__builtin_amdgcn_ds_bpermute(sl1, wbits));
      uint4 u0 = *(const uint4*)(hlin + ((size_t)r0 << 7) + ln * 8);
      uint4 u1 = *(const uint4*)(hlin + ((size_t)r1 << 7) + ln * 8);
      float2 f;
      f = bf2_to_f2(u0.x); acc[0] = fmaf(w0, f.x, acc[0]); acc[1] = fmaf(w0, f.y, acc[1]);
      f = bf2_to_f2(u0.y); acc[2] = fmaf(w0, f.x, acc[2]); acc[3] = fmaf(w0, f.y, acc[3]);
      f = bf2_to_f2(u0.z); acc[4] = fmaf(w0, f.x, acc[4]); acc[5] = fmaf(w0, f.y, acc[5]);
      f = bf2_to_f2(u0.w); acc[6] = fmaf(w0, f.x, acc[6]); acc[7] = fmaf(w0, f.y, acc[7]);
      f = bf2_to_f2(u1.x); acc[0] = fmaf(w1, f.x, acc[0]); acc[1] = fmaf(w1, f.y, acc[1]);
      f = bf2_to_f2(u1.y); acc[2] = fmaf(w1, f.x, acc[2]); acc[3] = fmaf(w1, f.y, acc[3]);
      f = bf2_to_f2(u1.z); acc[4] = fmaf(w1, f.x, acc[4]); acc[5] = fmaf(w1, f.y, acc[5]);
      f = bf2_to_f2(u1.w); acc[6] = fmaf(w1, f.x, acc[6]); acc[7] = fmaf(w1, f.y, acc[7]);
    }
  }

  // sum quads: lanes {ln, 16+ln, 32+ln, 48+ln}
  #pragma unroll
  for (int k = 0; k < 8; ++k) {
    acc[k] += __shfl_xor(acc[k], 16);
    acc[k] += __shfl_xor(acc[k], 32);
  }
  if (quad == 0) {
    uint4 o;
    o.x = f2_to_bf2(fmaxf(acc[0], 0.f), fmaxf(acc[1], 0.f));
    o.y = f2_to_bf2(fmaxf(acc[2], 0.f), fmaxf(acc[3], 0.f));
    o.z = f2_to_bf2(fmaxf(acc[4], 0.f), fmaxf(acc[5], 0.f));
    o.w = f2_to_bf2(fmaxf(acc[6], 0.f), fmaxf(acc[7], 0.f));
    *(uint4*)(hout2 + (size_t)node * 64 + ln * 4) = o;
  }
}

// ---------------- fused pool + MLP head (h4 is bf16, already relu'd) ------
__global__ __launch_bounds__(256) void k_poolmlp(const uint2* __restrict__ h4u,
                                                 const int* __restrict__ gstart,
                                                 const float* __restrict__ xs,
                                                 const float* __restrict__ Wl1,
                                                 const float* __restrict__ bl1,
                                                 const float* __restrict__ Wl2,
                                                 const float* __restrict__ bl2,
                                                 float* __restrict__ out) {
  __shared__ float4 part[8][32];
  __shared__ float pooled[128];
  int g = blockIdx.x;
  int beg = gstart[g], end = gstart[g + 1];
  int tid = threadIdx.x;
  int cg = tid & 31;
  int rg = tid >> 5;
  float4 acc = make_float4(0.f, 0.f, 0.f, 0.f);
  for (int i = beg + rg; i < end; i += 8) {
    uint2 u = h4u[(size_t)i * 32 + cg];
    acc.x += __uint_as_float(u.x << 16);
    acc.y += __uint_as_float(u.x & 0xffff0000u);
    acc.z += __uint_as_float(u.y << 16);
    acc.w += __uint_as_float(u.y & 0xffff0000u);
  }
  part[rg][cg] = acc;
  __syncthreads();
  if (tid < 32) {
    float4 s = part[0][tid];
    #pragma unroll
    for (int r = 1; r < 8; ++r) {
      float4 v = part[r][tid];
      s.x += v.x; s.y += v.y; s.z += v.z; s.w += v.w;
    }
    float sc = 1.f / fmaxf((float)(end - beg), 1.f);
    pooled[tid * 4 + 0] = s.x * sc;
    pooled[tid * 4 + 1] = s.y * sc;
    pooled[tid * 4 + 2] = s.z * sc;
    pooled[tid * 4 + 3] = s.w * sc;
  }
  __syncthreads();
  if (tid < 64) {
    float hj = bl1[tid];
    #pragma unroll 4
    for (int k = 0; k < 128; ++k) hj = fmaf(pooled[k], Wl1[k * 64 + tid], hj);
    const float* xr = xs + g * 4;
    #pragma unroll
    for (int k = 0; k < 4; ++k) hj = fmaf(xr[k], Wl1[(128 + k) * 64 + tid], hj);
    hj = fmaxf(hj, 0.f);
    float val = hj * Wl2[tid];
    #pragma unroll
    for (int off = 32; off > 0; off >>= 1) val += __shfl_down(val, off);
    if (tid == 0) out[g] = val + bl2[0];
  }
}

// ---------------- launcher ----------------

extern "C" void kernel_launch(void* const* d_in, const int* in_sizes, int n_in,
                              void* d_out, int out_size, void* d_ws, size_t ws_size,
                              hipStream_t stream) {
  const float* x    = (const float*)d_in[0];
  const int*   ei   = (const int*)d_in[1];
  const float* xs   = (const float*)d_in[2];
  const int*   batch= (const int*)d_in[3];
  const float* W0   = (const float*)d_in[4];
  const float* b0   = (const float*)d_in[5];
  const float* W1   = (const float*)d_in[6];
  const float* b1   = (const float*)d_in[7];
  const float* W2   = (const float*)d_in[8];
  const float* b2   = (const float*)d_in[9];
  const float* W3   = (const float*)d_in[10];
  const float* b3   = (const float*)d_in[11];
  const float* Wl1  = (const float*)d_in[12];
  const float* bl1  = (const float*)d_in[13];
  const float* Wl2  = (const float*)d_in[14];
  const float* bl2  = (const float*)d_in[15];
  const int* srcA = ei;        // edge_index[0]
  const int* dstA = ei + EE;   // edge_index[1]
  float* out = (float*)d_out;

  char* p = (char*)d_ws;
  auto take = [&](size_t bytes) { char* q = p; p += (bytes + 255) & ~(size_t)255; return q; };
  __bf16* hA   = (__bf16*)take((size_t)NN * 128 * 2);
  __bf16* hB   = (__bf16*)take((size_t)NN * 128 * 2);
  int*   cnt   = (int*)take((size_t)NN * 4);
  float* dinv  = (float*)take((size_t)NN * 4);
  int*   rowptr= (int*)take((size_t)(NN + 1) * 4);
  int*   fillc = (int*)take((size_t)NN * 4);
  int2*  csr   = (int2*)take((size_t)(EE + 7 * NN + 64) * 8);  // padded CSR
  int*   bsum  = (int*)take(512 * 4);
  int*   gstart= (int*)take((size_t)(GG + 1) * 4);
  __bf16* Wt1  = (__bf16*)take(16384 * 2);
  __bf16* Wt2  = (__bf16*)take(16384 * 2);
  __bf16* Wt3  = (__bf16*)take(16384 * 2);

  // setup: degree, norm+scan (padded to x8), CSR fill+pad, graph bounds, Wt
  k_init<<<NB, 256, 0, stream>>>(cnt, fillc, gstart);
  k_count<<<(EE + 255) / 256, 256, 0, stream>>>(dstA, cnt);
  k_scan1<<<NB, 256, 0, stream>>>(cnt, dinv, rowptr, bsum);
  k_scan2<<<1, 512, 0, stream>>>(bsum);
  k_scan3<<<NB, 256, 0, stream>>>(rowptr, bsum);
  k_fillpad<<<(EE + 255) / 256, 256, 0, stream>>>(srcA, dstA, rowptr, fillc, cnt, dinv, csr);
  k_gbound<<<NB, 256, 0, stream>>>(batch, gstart);
  k_wprep<<<64, 256, 0, stream>>>(W1, Wt1);
  k_wprep<<<64, 256, 0, stream>>>(W2, Wt2);
  k_wprep<<<64, 256, 0, stream>>>(W3, Wt3);

  // layer 0
  k_mm0<<<(NN * 128 + 255) / 256, 256, 0, stream>>>(x, W0, hA);
  k_aggregate<<<(NN + 3) / 4, 256, 0, stream>>>(hA, rowptr, csr, dinv, b0, (u32*)hB);
  // layers 1-3
  k_mfma<<<(NN + 127) / 128, 256, 0, stream>>>(hB, Wt1, hA);
  k_aggregate<<<(NN + 3) / 4, 256, 0, stream>>>(hA, rowptr, csr, dinv, b1, (u32*)hB);
  k_mfma<<<(NN + 127) / 128, 256, 0, stream>>>(hB, Wt2, hA);
  k_aggregate<<<(NN + 3) / 4, 256, 0, stream>>>(hA, rowptr, csr, dinv, b2, (u32*)hB);
  k_mfma<<<(NN + 127) / 128, 256, 0, stream>>>(hB, Wt3, hA);
  k_aggregate<<<(NN + 3) / 4, 256, 0, stream>>>(hA, rowptr, csr, dinv, b3, (u32*)hB);

  // fused pool + head MLP
  k_poolmlp<<<GG, 256, 0, stream>>>((const uint2*)hB, gstart, xs, Wl1, bl1, Wl2, bl2, out);
}

// Round 7
// 380.954 us; speedup vs baseline: 1.0872x; 1.0872x over previous
//
#include <hip/hip_runtime.h>

#define NN 100000
#define EE 600000
#define GG 1000
#define NB ((NN + 255) / 256)   // 391 blocks; also covers NN+1 scan elements

typedef __bf16 bf16x8 __attribute__((ext_vector_type(8)));
typedef float f32x4 __attribute__((ext_vector_type(4)));
typedef unsigned int u32;

__device__ inline float2 bf2_to_f2(u32 u) {
  return make_float2(__uint_as_float(u << 16), __uint_as_float(u & 0xffff0000u));
}
__device__ inline u32 f2_to_bf2(float a, float b) {
  union { __bf16 h[2]; u32 u; } pk;
  pk.h[0] = (__bf16)a; pk.h[1] = (__bf16)b;   // RNE converts
  return pk.u;
}

// ---------------- setup kernels (CSR build + norm) ----------------

__global__ void k_init(int* cnt, int* fillc, int* gstart) {
  int i = blockIdx.x * 256 + threadIdx.x;
  if (i < NN) { cnt[i] = 0; fillc[i] = 0; }
  if (i <= GG) gstart[i] = NN;
}

__global__ void k_count(const int* __restrict__ dst, int* cnt) {
  int e = blockIdx.x * 256 + threadIdx.x;
  if (e < EE) atomicAdd(&cnt[dst[e]], 1);
}

// scan over NN+1 elements of padded counts ((cnt+7)&~7); also computes dinv
__global__ void k_scan1(const int* __restrict__ cnt, float* __restrict__ dinv,
                        int* rowptr, int* bsum) {
  __shared__ int s[256];
  int tid = threadIdx.x;
  int i = blockIdx.x * 256 + tid;
  int v = (i < NN) ? ((cnt[i] + 7) & ~7) : 0;
  if (i < NN) dinv[i] = rsqrtf((float)(cnt[i] + 1));  // +1 = self loop
  s[tid] = v;
  __syncthreads();
  for (int off = 1; off < 256; off <<= 1) {
    int t = (tid >= off) ? s[tid - off] : 0;
    __syncthreads();
    s[tid] += t;
    __syncthreads();
  }
  if (i <= NN) rowptr[i] = s[tid] - v;
  if (tid == 255) bsum[blockIdx.x] = s[255];
}

__global__ void k_scan2(int* bsum) {
  __shared__ int s[512];
  int tid = threadIdx.x;
  int v = (tid < NB) ? bsum[tid] : 0;
  s[tid] = v;
  __syncthreads();
  for (int off = 1; off < 512; off <<= 1) {
    int t = (tid >= off) ? s[tid - off] : 0;
    __syncthreads();
    s[tid] += t;
    __syncthreads();
  }
  if (tid < NB) bsum[tid] = s[tid] - v;
}

__global__ void k_scan3(int* rowptr, const int* __restrict__ bsum) {
  int i = blockIdx.x * 256 + threadIdx.x;
  if (i <= NN) rowptr[i] += bsum[blockIdx.x];
}

// merged: CSR fill+pad (edge/node-parallel) + graph bounds + W transposes
__global__ void k_setup2(const int* __restrict__ src, const int* __restrict__ dst,
                         const int* __restrict__ rowptr, int* fillc,
                         const int* __restrict__ cnt,
                         const float* __restrict__ dinv,
                         int2* __restrict__ csr,
                         const int* __restrict__ batch, int* gstart,
                         const float* __restrict__ W1, const float* __restrict__ W2,
                         const float* __restrict__ W3,
                         __bf16* __restrict__ Wt1, __bf16* __restrict__ Wt2,
                         __bf16* __restrict__ Wt3) {
  int gid = blockIdx.x * 256 + threadIdx.x;
  if (gid < EE) {
    int s = src[gid], d = dst[gid];
    int pos = rowptr[d] + atomicAdd(&fillc[d], 1);
    csr[pos] = make_int2(s, __float_as_int(dinv[s] * dinv[d]));
  }
  if (gid < NN) {
    int2 pad = make_int2(gid, 0);   // w=0 no-op self edge
    for (int pos = rowptr[gid] + cnt[gid]; pos < rowptr[gid + 1]; ++pos)
      csr[pos] = pad;
    // graph boundaries (batch sorted)
    int b = batch[gid];
    if (gid == 0) {
      for (int g = 0; g <= b; ++g) gstart[g] = 0;
    } else {
      int prev = batch[gid - 1];
      for (int g = prev + 1; g <= b; ++g) gstart[g] = gid;
    }
  }
  if (gid < 3 * 16384) {   // W transposes: [k][n] fp32 -> [n][k] bf16
    int which = gid >> 14, idx = gid & 16383;
    int n = idx >> 7, k = idx & 127;
    const float* W = (which == 0) ? W1 : (which == 1) ? W2 : W3;
    __bf16* Wt = (which == 0) ? Wt1 : (which == 1) ? Wt2 : Wt3;
    Wt[(size_t)n * 128 + k] = (__bf16)W[(size_t)k * 128 + n];
  }
}

// ---------------- layer kernels ----------------

// 4-dim aggregate over x (linearity: Agg(x@W0) = Agg(x)@W0).
// x rows are 16B; whole x is 1.6MB -> L2-resident, gather is cheap.
__global__ void k_aggx(const float4* __restrict__ x, const int* __restrict__ rowptr,
                       const int* __restrict__ cnt, const int2* __restrict__ csr,
                       const float* __restrict__ dinv, float4* __restrict__ y) {
  int i = blockIdx.x * 256 + threadIdx.x;
  if (i >= NN) return;
  float di = dinv[i];
  float sw = di * di;
  float4 xi = x[i];
  float4 acc = make_float4(sw * xi.x, sw * xi.y, sw * xi.z, sw * xi.w);
  int beg = rowptr[i], end = beg + cnt[i];   // unpadded extent
  for (int e = beg; e < end; ++e) {
    int2 md = csr[e];
    float w = __int_as_float(md.y);
    float4 v = x[md.x];
    acc.x = fmaf(w, v.x, acc.x);
    acc.y = fmaf(w, v.y, acc.y);
    acc.z = fmaf(w, v.z, acc.z);
    acc.w = fmaf(w, v.w, acc.w);
  }
  y[i] = acc;
}

// h0 = relu(y @ W0 + b0) -> bf16  ([N,4]@[4,128])
__global__ void k_lin0(const float4* __restrict__ y, const float* __restrict__ W0,
                       const float* __restrict__ b0, __bf16* __restrict__ hout) {
  int idx = blockIdx.x * 256 + threadIdx.x;
  if (idx >= NN * 128) return;
  int node = idx >> 7, j = idx & 127;
  float4 yv = y[node];
  float s = b0[j];
  s = fmaf(yv.x, W0[j], s);
  s = fmaf(yv.y, W0[128 + j], s);
  s = fmaf(yv.z, W0[256 + j], s);
  s = fmaf(yv.w, W0[384 + j], s);
  hout[idx] = (__bf16)fmaxf(s, 0.f);
}

// MFMA GEMM with fused bias+relu epilogue:
// hout[N,128] = relu(hin[N,128] @ W + bias), bf16 in/out, fp32 accum.
#define LDSPAD 136
__global__ __launch_bounds__(256) void k_mfma(const __bf16* __restrict__ hin,
                                              const __bf16* __restrict__ Wt,
                                              const float* __restrict__ bias,
                                              __bf16* __restrict__ hout) {
  __shared__ __bf16 As[128 * LDSPAD];   // 34 KB
  int tid = threadIdx.x;
  int row0 = blockIdx.x * 128;
  int lane = tid & 63, w = tid >> 6;
  int ln = lane & 15, quad = lane >> 4;

  bf16x8 bfrag[8][4];
  float bcol[8];
  #pragma unroll
  for (int nt = 0; nt < 8; ++nt) {
    bcol[nt] = bias[nt * 16 + ln];
    #pragma unroll
    for (int kc = 0; kc < 4; ++kc)
      bfrag[nt][kc] = *(const bf16x8*)(Wt + (size_t)(nt * 16 + ln) * 128 + kc * 32 + quad * 8);
  }

  #pragma unroll
  for (int i = 0; i < 8; ++i) {
    int eb = (i * 256 + tid) * 8;
    int r = eb >> 7, c = eb & 127;
    int gr = row0 + r;
    uint4 v = make_uint4(0, 0, 0, 0);
    if (gr < NN) v = *(const uint4*)(hin + (size_t)gr * 128 + c);
    *(uint4*)&As[r * LDSPAD + c] = v;
  }
  __syncthreads();

  f32x4 acc[2][8];
  #pragma unroll
  for (int rt = 0; rt < 2; ++rt)
    #pragma unroll
    for (int nt = 0; nt < 8; ++nt) acc[rt][nt] = (f32x4){0.f, 0.f, 0.f, 0.f};

  #pragma unroll
  for (int kc = 0; kc < 4; ++kc) {
    bf16x8 a0 = *(const bf16x8*)&As[(w * 32 + ln) * LDSPAD + kc * 32 + quad * 8];
    bf16x8 a1 = *(const bf16x8*)&As[(w * 32 + 16 + ln) * LDSPAD + kc * 32 + quad * 8];
    #pragma unroll
    for (int nt = 0; nt < 8; ++nt) {
      acc[0][nt] = __builtin_amdgcn_mfma_f32_16x16x32_bf16(a0, bfrag[nt][kc], acc[0][nt], 0, 0, 0);
      acc[1][nt] = __builtin_amdgcn_mfma_f32_16x16x32_bf16(a1, bfrag[nt][kc], acc[1][nt], 0, 0, 0);
    }
  }

  // C layout: row=(lane>>4)*4+reg, col=lane&15; epilogue = +bias, relu
  #pragma unroll
  for (int rt = 0; rt < 2; ++rt)
    #pragma unroll
    for (int nt = 0; nt < 8; ++nt)
      #pragma unroll
      for (int reg = 0; reg < 4; ++reg) {
        int gr = row0 + w * 32 + rt * 16 + quad * 4 + reg;
        if (gr < NN)
          hout[(size_t)gr * 128 + nt * 16 + ln] =
              (__bf16)fmaxf(acc[rt][nt][reg] + bcol[nt], 0.f);
      }
}

// g[i] = dinv[i]^2*h[i] + sum_e w[e]*h[src[e]]  (no bias/relu; they moved
// into the following mfma's epilogue). bf16 in/out, fp32 accum.
// Quad q gathers edge j+q (16 lanes x 16B = 256B row); CSR padded to x8.
__global__ __launch_bounds__(256) void k_aggregate(const __bf16* __restrict__ hlin,
                                                   const int* __restrict__ rowptr,
                                                   const int2* __restrict__ csr,
                                                   const float* __restrict__ dinv,
                                                   u32* __restrict__ hout2) {
  int node = blockIdx.x * 4 + (threadIdx.x >> 6);
  int lane = threadIdx.x & 63;
  int ln = lane & 15, quad = lane >> 4;
  if (node >= NN) return;
  float di = dinv[node];
  float sw = di * di;

  // self term (quad 0 only; other quads start at zero)
  uint4 su = *(const uint4*)(hlin + ((size_t)node << 7) + ln * 8);
  float2 s0 = bf2_to_f2(su.x), s1 = bf2_to_f2(su.y);
  float2 s2 = bf2_to_f2(su.z), s3 = bf2_to_f2(su.w);
  float q0 = (quad == 0) ? sw : 0.f;
  float acc[8];
  acc[0] = q0 * s0.x; acc[1] = q0 * s0.y;
  acc[2] = q0 * s1.x; acc[3] = q0 * s1.y;
  acc[4] = q0 * s2.x; acc[5] = q0 * s2.y;
  acc[6] = q0 * s3.x; acc[7] = q0 * s3.y;

  int beg = rowptr[node], end = rowptr[node + 1];
  for (int base = beg; base < end; base += 64) {
    int m = end - base; if (m > 64) m = 64;           // multiple of 8
    int li = base + (lane < m ? lane : m - 1);
    int2 md = csr[li];
    int idxv = md.x, wbits = md.y;
    for (int j = 0; j < m; j += 8) {
      int sl0 = (j + quad) * 4, sl1 = (j + 4 + quad) * 4;
      int r0 = __builtin_amdgcn_ds_bpermute(sl0, idxv);
      int r1 = __builtin_amdgcn_ds_bpermute(sl1, idxv);
      float w0 = __int_as_float(__builtin_amdgcn_ds_bpermute(sl0, wbits));
      float w1 = __int_as_float(__builtin_amdgcn_ds_bpermute(sl1, wbits));
      uint4 u0 = *(const uint4*)(hlin + ((size_t)r0 << 7) + ln * 8);
      uint4 u1 = *(const uint4*)(hlin + ((size_t)r1 << 7) + ln * 8);
      float2 f;
      f = bf2_to_f2(u0.x); acc[0] = fmaf(w0, f.x, acc[0]); acc[1] = fmaf(w0, f.y, acc[1]);
      f = bf2_to_f2(u0.y); acc[2] = fmaf(w0, f.x, acc[2]); acc[3] = fmaf(w0, f.y, acc[3]);
      f = bf2_to_f2(u0.z); acc[4] = fmaf(w0, f.x, acc[4]); acc[5] = fmaf(w0, f.y, acc[5]);
      f = bf2_to_f2(u0.w); acc[6] = fmaf(w0, f.x, acc[6]); acc[7] = fmaf(w0, f.y, acc[7]);
      f = bf2_to_f2(u1.x); acc[0] = fmaf(w1, f.x, acc[0]); acc[1] = fmaf(w1, f.y, acc[1]);
      f = bf2_to_f2(u1.y); acc[2] = fmaf(w1, f.x, acc[2]); acc[3] = fmaf(w1, f.y, acc[3]);
      f = bf2_to_f2(u1.z); acc[4] = fmaf(w1, f.x, acc[4]); acc[5] = fmaf(w1, f.y, acc[5]);
      f = bf2_to_f2(u1.w); acc[6] = fmaf(w1, f.x, acc[6]); acc[7] = fmaf(w1, f.y, acc[7]);
    }
  }

  #pragma unroll
  for (int k = 0; k < 8; ++k) {
    acc[k] += __shfl_xor(acc[k], 16);
    acc[k] += __shfl_xor(acc[k], 32);
  }
  if (quad == 0) {
    uint4 o;
    o.x = f2_to_bf2(acc[0], acc[1]);
    o.y = f2_to_bf2(acc[2], acc[3]);
    o.z = f2_to_bf2(acc[4], acc[5]);
    o.w = f2_to_bf2(acc[6], acc[7]);
    *(uint4*)(hout2 + (size_t)node * 64 + ln * 4) = o;
  }
}

// ---------------- fused pool + MLP head (h3 is bf16, already relu'd) ------
__global__ __launch_bounds__(256) void k_poolmlp(const uint2* __restrict__ h4u,
                                                 const int* __restrict__ gstart,
                                                 const float* __restrict__ xs,
                                                 const float* __restrict__ Wl1,
                                                 const float* __restrict__ bl1,
                                                 const float* __restrict__ Wl2,
                                                 const float* __restrict__ bl2,
                                                 float* __restrict__ out) {
  __shared__ float4 part[8][32];
  __shared__ float pooled[128];
  int g = blockIdx.x;
  int beg = gstart[g], end = gstart[g + 1];
  int tid = threadIdx.x;
  int cg = tid & 31;
  int rg = tid >> 5;
  float4 acc = make_float4(0.f, 0.f, 0.f, 0.f);
  for (int i = beg + rg; i < end; i += 8) {
    uint2 u = h4u[(size_t)i * 32 + cg];
    acc.x += __uint_as_float(u.x << 16);
    acc.y += __uint_as_float(u.x & 0xffff0000u);
    acc.z += __uint_as_float(u.y << 16);
    acc.w += __uint_as_float(u.y & 0xffff0000u);
  }
  part[rg][cg] = acc;
  __syncthreads();
  if (tid < 32) {
    float4 s = part[0][tid];
    #pragma unroll
    for (int r = 1; r < 8; ++r) {
      float4 v = part[r][tid];
      s.x += v.x; s.y += v.y; s.z += v.z; s.w += v.w;
    }
    float sc = 1.f / fmaxf((float)(end - beg), 1.f);
    pooled[tid * 4 + 0] = s.x * sc;
    pooled[tid * 4 + 1] = s.y * sc;
    pooled[tid * 4 + 2] = s.z * sc;
    pooled[tid * 4 + 3] = s.w * sc;
  }
  __syncthreads();
  if (tid < 64) {
    float hj = bl1[tid];
    #pragma unroll 4
    for (int k = 0; k < 128; ++k) hj = fmaf(pooled[k], Wl1[k * 64 + tid], hj);
    const float* xr = xs + g * 4;
    #pragma unroll
    for (int k = 0; k < 4; ++k) hj = fmaf(xr[k], Wl1[(128 + k) * 64 + tid], hj);
    hj = fmaxf(hj, 0.f);
    float val = hj * Wl2[tid];
    #pragma unroll
    for (int off = 32; off > 0; off >>= 1) val += __shfl_down(val, off);
    if (tid == 0) out[g] = val + bl2[0];
  }
}

// ---------------- launcher ----------------

extern "C" void kernel_launch(void* const* d_in, const int* in_sizes, int n_in,
                              void* d_out, int out_size, void* d_ws, size_t ws_size,
                              hipStream_t stream) {
  const float* x    = (const float*)d_in[0];
  const int*   ei   = (const int*)d_in[1];
  const float* xs   = (const float*)d_in[2];
  const int*   batch= (const int*)d_in[3];
  const float* W0   = (const float*)d_in[4];
  const float* b0   = (const float*)d_in[5];
  const float* W1   = (const float*)d_in[6];
  const float* b1   = (const float*)d_in[7];
  const float* W2   = (const float*)d_in[8];
  const float* b2   = (const float*)d_in[9];
  const float* W3   = (const float*)d_in[10];
  const float* b3   = (const float*)d_in[11];
  const float* Wl1  = (const float*)d_in[12];
  const float* bl1  = (const float*)d_in[13];
  const float* Wl2  = (const float*)d_in[14];
  const float* bl2  = (const float*)d_in[15];
  const int* srcA = ei;        // edge_index[0]
  const int* dstA = ei + EE;   // edge_index[1]
  float* out = (float*)d_out;

  char* p = (char*)d_ws;
  auto take = [&](size_t bytes) { char* q = p; p += (bytes + 255) & ~(size_t)255; return q; };
  __bf16* hA   = (__bf16*)take((size_t)NN * 128 * 2);
  __bf16* hB   = (__bf16*)take((size_t)NN * 128 * 2);
  float*  y    = (float*)take((size_t)NN * 4 * 4);
  int*   cnt   = (int*)take((size_t)NN * 4);
  float* dinv  = (float*)take((size_t)NN * 4);
  int*   rowptr= (int*)take((size_t)(NN + 1) * 4);
  int*   fillc = (int*)take((size_t)NN * 4);
  int2*  csr   = (int2*)take((size_t)(EE + 7 * NN + 64) * 8);  // padded CSR
  int*   bsum  = (int*)take(512 * 4);
  int*   gstart= (int*)take((size_t)(GG + 1) * 4);
  __bf16* Wt1  = (__bf16*)take(16384 * 2);
  __bf16* Wt2  = (__bf16*)take(16384 * 2);
  __bf16* Wt3  = (__bf16*)take(16384 * 2);

  // setup
  k_init<<<NB, 256, 0, stream>>>(cnt, fillc, gstart);
  k_count<<<(EE + 255) / 256, 256, 0, stream>>>(dstA, cnt);
  k_scan1<<<NB, 256, 0, stream>>>(cnt, dinv, rowptr, bsum);
  k_scan2<<<1, 512, 0, stream>>>(bsum);
  k_scan3<<<NB, 256, 0, stream>>>(rowptr, bsum);
  k_setup2<<<(EE + 255) / 256, 256, 0, stream>>>(srcA, dstA, rowptr, fillc, cnt, dinv,
                                                 csr, batch, gstart, W1, W2, W3,
                                                 Wt1, Wt2, Wt3);

  // layer 0 via linearity: y = Agg(x) (4-dim, L2-hot), h0 = relu(y@W0+b0)
  k_aggx<<<NB, 256, 0, stream>>>((const float4*)x, rowptr, cnt, csr, dinv, (float4*)y);
  k_lin0<<<(NN * 128 + 255) / 256, 256, 0, stream>>>((const float4*)y, W0, b0, hA);
  // layers 1-3: g = Agg(h) (128-dim gather), h' = relu(g@W + b) via MFMA
  k_aggregate<<<(NN + 3) / 4, 256, 0, stream>>>(hA, rowptr, csr, dinv, (u32*)hB);
  k_mfma<<<(NN + 127) / 128, 256, 0, stream>>>(hB, Wt1, b1, hA);
  k_aggregate<<<(NN + 3) / 4, 256, 0, stream>>>(hA, rowptr, csr, dinv, (u32*)hB);
  k_mfma<<<(NN + 127) / 128, 256, 0, stream>>>(hB, Wt2, b2, hA);
  k_aggregate<<<(NN + 3) / 4, 256, 0, stream>>>(hA, rowptr, csr, dinv, (u32*)hB);
  k_mfma<<<(NN + 127) / 128, 256, 0, stream>>>(hB, Wt3, b3, hA);

  // fused pool + head MLP
  k_poolmlp<<<GG, 256, 0, stream>>>((const uint2*)hA, gstart, xs, Wl1, bl1, Wl2, bl2, out);
}